// Round 9
// baseline (367.235 us; speedup 1.0000x reference)
//
#include <hip/hip_runtime.h>
#include <math.h>
#include <stdint.h>

namespace {

constexpr int T = 50;
constexpr int NB = 32768;
constexpr int H = 128;
constexpr int NTHREADS = 256;   // 4 waves; each wave owns 32 output cols
constexpr int BLK_ROWS = 32;    // 2 M-tiles of 16 rows
constexpr int SH_STRIDE = 132;  // u32 words per h row (128 + 4 pad)

typedef float v4f __attribute__((ext_vector_type(4)));
typedef float v2f __attribute__((ext_vector_type(2)));
typedef unsigned int v4u __attribute__((ext_vector_type(4)));
typedef short short8 __attribute__((ext_vector_type(8)));

union FU { float f; uint32_t u; };
union U8 { uint32_t u[4]; short8 v; };

// v_perm_b32 byte-select packers (1 VALU op each)
__device__ __forceinline__ uint32_t perm_hi(uint32_t odd, uint32_t even) {
  return __builtin_amdgcn_perm(odd, even, 0x07060302u);   // top16:top16
}
__device__ __forceinline__ uint32_t perm_lo(uint32_t odd, uint32_t even) {
  return __builtin_amdgcn_perm(odd, even, 0x05040100u);   // low16:low16
}

// force wave-uniform float into SGPR
__device__ __forceinline__ float rfl(float x) {
  FU a; a.f = x;
  FU b; b.u = (uint32_t)__builtin_amdgcn_readfirstlane((int)a.u);
  return b.f;
}

// 2-way bf16 split, raw words: top16(araw)=hi plane, top16(rraw)=mid plane
__device__ __forceinline__ void split2raw(float a, uint32_t& araw, uint32_t& rraw) {
  FU c0; c0.f = a;
  FU fh; fh.u = c0.u & 0xFFFF0000u;
  FU r;  r.f  = a - fh.f;   // exact
  araw = c0.u; rraw = r.u;
}
// 3-way exact bf16 split (prologue only)
__device__ __forceinline__ void split3(float a, uint32_t& hi, uint32_t& mid, uint32_t& lo) {
  FU c0; c0.f = a;
  uint32_t uh = c0.u & 0xFFFF0000u;
  FU fh; fh.u = uh;
  float r1 = a - fh.f;
  FU c1; c1.f = r1;
  uint32_t um = c1.u & 0xFFFF0000u;
  FU fm; fm.u = um;
  float r2 = r1 - fm.f;
  FU c2; c2.f = r2;
  hi = uh; mid = um; lo = c2.u;
}

__device__ __forceinline__ v4f mfma16(short8 a, short8 b, v4f c) {
  return __builtin_amdgcn_mfma_f32_16x16x32_bf16(a, b, c, 0, 0, 0);
}

// LDS-only block barrier: drains lgkm (DS) but NOT vmcnt.
__device__ __forceinline__ void block_sync_lds() {
  asm volatile("s_waitcnt lgkmcnt(0)" ::: "memory");
  __builtin_amdgcn_s_barrier();
  asm volatile("" ::: "memory");
}

// VALU-pipe butterfly add
template<int CTRL>
__device__ __forceinline__ float dpp_radd(float x) {
  FU a; a.f = x;
  FU b; b.u = (uint32_t)__builtin_amdgcn_update_dpp(0, (int)a.u, CTRL, 0xF, 0xF, true);
  return x + b.f;
}
// sum over the 16 lanes of each lane-group (o = lane&15)
__device__ __forceinline__ float red16(float x) {
  x = dpp_radd<0xB1>(x);    // quad_perm xor1
  x = dpp_radd<0x4E>(x);    // quad_perm xor2
  x = dpp_radd<0x141>(x);   // row_half_mirror (xor4)
  x = dpp_radd<0x140>(x);   // row_mirror (xor8)
  return x;
}

__global__ __launch_bounds__(NTHREADS, 3)   // target 3 waves/SIMD (cap ~170 regs)
void fwdsim11(const float* __restrict__ proj,   // (B, 64)
              const float* __restrict__ idm,    // (B, T, 12)
              const float* __restrict__ merg,   // (B, T, 3)
              const float* __restrict__ W1,     // (73, 128)
              const float* __restrict__ b1,     // (128)
              const float* __restrict__ W2,     // (128, 128)
              const float* __restrict__ b2,     // (128)
              const float* __restrict__ W3,     // (128, 1)
              const float* __restrict__ b3,     // (1)
              const float* __restrict__ smean,  // (6)
              const float* __restrict__ svar,   // (6)
              float* __restrict__ out)          // (B, T)
{
  // h exchange: [row 32][132] packed bf16 hi|mid
  __shared__ __align__(16) uint32_t sH[BLK_ROWS * SH_STRIDE];   // 16896 B
  // base1 (b1 + proj@W1[0:64]) fp32, wave-private: [col 128][row pad 36]
  __shared__ __align__(16) float sBase[128 * 36];               // 18432 B
  // layer-3 partials: [buf][row 32][member 4]
  __shared__ __align__(16) float sAct[2][BLK_ROWS][4];          // 1024 B
  // output staging (coalesced flush at end)
  __shared__ __align__(16) float sOut[BLK_ROWS * T];            // 6400 B
  // total 42752 B -> 3 blocks/CU by LDS (matches 3 waves/SIMD target)

  const int tid  = threadIdx.x;
  const int wave = tid >> 6;    // 0..3: owns output cols wave*32 .. wave*32+31
  const int lane = tid & 63;
  const int gq   = lane >> 4;   // 0..3
  const int o    = lane & 15;   // 0..15
  const int row0 = blockIdx.x * BLK_ROWS;

  // ---- wave-uniform scalars -> SGPR via readfirstlane ----
  float istd[6], off[6];
#pragma unroll
  for (int c = 0; c < 6; ++c) {
    const float is = rfl(1.0f / sqrtf(svar[c]));
    istd[c] = is;
    off[c]  = rfl(-smean[c] * is);
  }
  const float b3v = rfl(b3[0]);
  float b2c[2], W3c[2];
#pragma unroll
  for (int ntl = 0; ntl < 2; ++ntl) {
    const int n = (wave * 2 + ntl) * 16 + o;
    b2c[ntl] = b2[n]; W3c[ntl] = W3[n];
  }

  // ---- W1 env rows 64..72 -> persistent register B-frags (2-plane, K pad 32) ----
  short8 ebh[2], ebm[2];
#pragma unroll
  for (int ntl = 0; ntl < 2; ++ntl) {
    const int n = (wave * 2 + ntl) * 16 + o;
    uint32_t hr[8], mr[8];
#pragma unroll
    for (int j = 0; j < 8; ++j) {
      const int k = gq * 8 + j;
      const float w = (k < 9) ? W1[(64 + k) * H + n] : 0.f;
      split2raw(w, hr[j], mr[j]);
    }
    U8 fh, fm;
#pragma unroll
    for (int d = 0; d < 4; ++d) {
      fh.u[d] = perm_hi(hr[2*d+1], hr[2*d]);
      fm.u[d] = perm_hi(mr[2*d+1], mr[2*d]);
    }
    ebh[ntl] = fh.v; ebm[ntl] = fm.v;
  }

  // ---- prologue: base1 = b1 + proj @ W1[0:64] (3-plane exact) -> sBase ----
  {
    // W1[0:64] 3-plane frags (prologue-lifetime registers)
    short8 w1h[4], w1m[4], w1l[4];   // [kt*2+ntl]
#pragma unroll
    for (int kt = 0; kt < 2; ++kt)
#pragma unroll
      for (int ntl = 0; ntl < 2; ++ntl) {
        const int k0 = kt * 32 + gq * 8;
        const int n  = (wave * 2 + ntl) * 16 + o;
        uint32_t hi[8], mi[8], lo[8];
#pragma unroll
        for (int j = 0; j < 8; ++j) split3(W1[(k0 + j) * H + n], hi[j], mi[j], lo[j]);
        U8 fh, fm, fl;
#pragma unroll
        for (int d = 0; d < 4; ++d) {
          fh.u[d] = perm_hi(hi[2*d+1], hi[2*d]);
          fm.u[d] = perm_hi(mi[2*d+1], mi[2*d]);
          fl.u[d] = perm_hi(lo[2*d+1], lo[2*d]);
        }
        w1h[kt*2+ntl] = fh.v; w1m[kt*2+ntl] = fm.v; w1l[kt*2+ntl] = fl.v;
      }

    float b1c[2];
#pragma unroll
    for (int ntl = 0; ntl < 2; ++ntl) b1c[ntl] = b1[(wave*2+ntl)*16 + o];

#pragma unroll
    for (int mt = 0; mt < 2; ++mt) {
      const int row = row0 + mt * 16 + o;
      short8 pah[2], pam[2], pal[2];
#pragma unroll
      for (int kt = 0; kt < 2; ++kt) {
        const float* pp = proj + (size_t)row * 64 + kt * 32 + gq * 8;
        v4f p0 = *(const v4f*)pp;
        v4f p1 = *(const v4f*)(pp + 4);
        uint32_t hi[8], mi[8], lo[8];
#pragma unroll
        for (int e = 0; e < 4; ++e) split3(p0[e], hi[e],   mi[e],   lo[e]);
#pragma unroll
        for (int e = 0; e < 4; ++e) split3(p1[e], hi[4+e], mi[4+e], lo[4+e]);
        U8 uh, um, ul;
#pragma unroll
        for (int d = 0; d < 4; ++d) {
          uh.u[d] = perm_hi(hi[2*d+1], hi[2*d]);
          um.u[d] = perm_hi(mi[2*d+1], mi[2*d]);
          ul.u[d] = perm_hi(lo[2*d+1], lo[2*d]);
        }
        pah[kt] = uh.v; pam[kt] = um.v; pal[kt] = ul.v;
      }
#pragma unroll
      for (int ntl = 0; ntl < 2; ++ntl) {
        v4f acc = (v4f){b1c[ntl], b1c[ntl], b1c[ntl], b1c[ntl]};
#pragma unroll
        for (int kt = 0; kt < 2; ++kt) {
          short8 bh = w1h[kt*2+ntl], bm = w1m[kt*2+ntl], bl = w1l[kt*2+ntl];
          acc = mfma16(pah[kt], bl, acc);
          acc = mfma16(pal[kt], bh, acc);
          acc = mfma16(pam[kt], bm, acc);
          acc = mfma16(pah[kt], bm, acc);
          acc = mfma16(pam[kt], bh, acc);
          acc = mfma16(pah[kt], bh, acc);
        }
        // wave-private store; layout matches phase-A C-operand read
        *(v4f*)&sBase[(((wave*2+ntl)*16 + o) * 36) + mt*16 + 4*gq] = acc;
      }
    }
  }

  // ---- W2 -> persistent register B-frags, 2-plane (R4-proven form) ----
  short8 w2h[8], w2m[8];   // [kt*2+ntl], kt 0..3  (64 regs)
#pragma unroll
  for (int kt = 0; kt < 4; ++kt)
#pragma unroll
    for (int ntl = 0; ntl < 2; ++ntl) {
      const int k0 = kt * 32 + gq * 8;
      const int n  = (wave * 2 + ntl) * 16 + o;
      uint32_t hr[8], mr[8];
#pragma unroll
      for (int j = 0; j < 8; ++j) split2raw(W2[(k0 + j) * H + n], hr[j], mr[j]);
      U8 fh, fm;
#pragma unroll
      for (int d = 0; d < 4; ++d) {
        fh.u[d] = perm_hi(hr[2*d+1], hr[2*d]);
        fm.u[d] = perm_hi(mr[2*d+1], mr[2*d]);
      }
      w2h[kt*2+ntl] = fh.v;
      w2m[kt*2+ntl] = fm.v;
    }

  // ---- recurrent state: 32-bit byte offsets off SGPR bases ----
  float ego_v[2], ego_x[2], act[2] = {0.f, 0.f};
  uint32_t ib[2], mb[2];
  v4f sa[2]; v2f fb[2]; float exr[2], m0[2], m1[2], m2[2];
#pragma unroll
  for (int mt = 0; mt < 2; ++mt) {
    const uint32_t row = row0 + mt*16 + o;
    ib[mt] = row * (uint32_t)(T*12*4);
    mb[mt] = row * (uint32_t)(T*3*4);
    const char* ip = (const char*)idm + ib[mt];
    sa[mt] = *(const v4f*)ip;
    fb[mt] = *(const v2f*)(ip + 16);
    exr[mt] = *(const float*)(ip + 44);
    const char* mp = (const char*)merg + mb[mt];
    m0[mt] = *(const float*)mp;
    m1[mt] = *(const float*)(mp + 4);
    m2[mt] = *(const float*)(mp + 8);
  }

  block_sync_lds();   // sBase writes ordered before loop reads
  int buf = 0;

#pragma unroll 1
  for (int t = 0; t < T; ++t) {
    // ======== phase A: state + env ========
    float xk[2][9];
#pragma unroll
    for (int mt = 0; mt < 2; ++mt) {
      const float s0 = sa[mt][0], fv = sa[mt][1], mv = sa[mt][2], s3 = sa[mt][3];
      const float fgx = fb[mt][0], mgx = fb[mt][1];
      const float ex = exr[mt];
      if (t == 0) { ego_v[mt] = s0; ego_x[mt] = s3; }
      else {
        ego_v[mt] += act[mt] * 0.1f;
        ego_x[mt] += ego_v[mt] * 0.1f + act[mt] * 0.005f;
      }
      xk[mt][0] = ego_v[mt]                                       * istd[0] + off[0];
      xk[mt][1] = fv                                              * istd[1] + off[1];
      xk[mt][2] = (ego_v[mt] - fv)                                * istd[2] + off[2];
      xk[mt][3] = (fgx - ego_x[mt])                               * istd[3] + off[3];
      xk[mt][4] = ((ego_v[mt] - mv) * ex)                         * istd[4] + off[4];
      xk[mt][5] = ((mgx - ego_x[mt]) * ex + (1.0f - ex) * 100.0f) * istd[5] + off[5];
      xk[mt][6] = m0[mt]; xk[mt][7] = m1[mt]; xk[mt][8] = m2[mt];
    }

    // reload next step's inputs in place (fly across lgkm-only barriers)
    {
      const uint32_t adv = (t + 1 < T) ? 1u : 0u;
#pragma unroll
      for (int mt = 0; mt < 2; ++mt) {
        ib[mt] += adv * 48u; mb[mt] += adv * 12u;
        const char* ip = (const char*)idm + ib[mt];
        sa[mt] = *(const v4f*)ip;
        fb[mt] = *(const v2f*)(ip + 16);
        exr[mt] = *(const float*)(ip + 44);
        const char* mp = (const char*)merg + mb[mt];
        m0[mt] = *(const float*)mp;
        m1[mt] = *(const float*)(mp + 4);
        m2[mt] = *(const float*)(mp + 8);
      }
    }

    // ---- layer 1 -> packed h -> sH (own 32 cols) ----
#pragma unroll
    for (int mt = 0; mt < 2; ++mt) {
      uint32_t hr[8], mr[8];
#pragma unroll
      for (int j = 0; j < 8; ++j) {
        float v = (gq == 0) ? xk[mt][j] : ((gq == 1 && j == 0) ? xk[mt][8] : 0.f);
        split2raw(v, hr[j], mr[j]);
      }
      U8 uh, um;
#pragma unroll
      for (int d = 0; d < 4; ++d) {
        uh.u[d] = perm_hi(hr[2*d+1], hr[2*d]);
        um.u[d] = perm_hi(mr[2*d+1], mr[2*d]);
      }
      short8 eh = uh.v, em = um.v;

#pragma unroll
      for (int ntl = 0; ntl < 2; ++ntl) {
        v4f a1 = *(const v4f*)&sBase[(((wave*2+ntl)*16 + o) * 36) + mt*16 + 4*gq];
        a1 = mfma16(eh, ebm[ntl], a1);
        a1 = mfma16(em, ebh[ntl], a1);
        a1 = mfma16(eh, ebh[ntl], a1);
#pragma unroll
        for (int r = 0; r < 4; ++r) {
          const float hv = fmaxf(a1[r], 0.f);
          uint32_t hu, ru; split2raw(hv, hu, ru);
          sH[(mt*16 + 4*gq + r) * SH_STRIDE + (wave*2+ntl)*16 + o] = perm_hi(hu, ru);
        }
      }
    }

    block_sync_lds();   // B1: full h visible (vmcnt NOT drained)

    // ======== phase B: layer 2 (full K from sH) + layer-3 partial ========
#pragma unroll
    for (int mt = 0; mt < 2; ++mt) {
      v4f acc2[2];
#pragma unroll
      for (int ntl = 0; ntl < 2; ++ntl)
        acc2[ntl] = (v4f){b2c[ntl], b2c[ntl], b2c[ntl], b2c[ntl]};

#pragma unroll
      for (int kt = 0; kt < 4; ++kt) {
        const uint32_t* src = &sH[(mt*16 + o) * SH_STRIDE + kt*32 + gq*8];
        v4u q0 = *(const v4u*)src;
        v4u q1 = *(const v4u*)(src + 4);
        U8 uh, um;
        uh.u[0] = perm_hi(q0[1], q0[0]);  um.u[0] = perm_lo(q0[1], q0[0]);
        uh.u[1] = perm_hi(q0[3], q0[2]);  um.u[1] = perm_lo(q0[3], q0[2]);
        uh.u[2] = perm_hi(q1[1], q1[0]);  um.u[2] = perm_lo(q1[1], q1[0]);
        uh.u[3] = perm_hi(q1[3], q1[2]);  um.u[3] = perm_lo(q1[3], q1[2]);
        short8 ah = uh.v, am = um.v;
#pragma unroll
        for (int ntl = 0; ntl < 2; ++ntl) {
          acc2[ntl] = mfma16(ah, w2m[kt*2+ntl], acc2[ntl]);
          acc2[ntl] = mfma16(am, w2h[kt*2+ntl], acc2[ntl]);
          acc2[ntl] = mfma16(ah, w2h[kt*2+ntl], acc2[ntl]);
        }
      }

      // layer-3 partial over this wave's 32 cols
      v4f part = (v4f){0.f, 0.f, 0.f, 0.f};
#pragma unroll
      for (int ntl = 0; ntl < 2; ++ntl)
#pragma unroll
        for (int r = 0; r < 4; ++r)
          part[r] += fmaxf(acc2[ntl][r], 0.f) * W3c[ntl];
#pragma unroll
      for (int r = 0; r < 4; ++r) part[r] = red16(part[r]);

      // spread store: lane (gq, o<4) writes row mt*16+4gq+o
      const float pv = (o & 2) ? ((o & 1) ? part[3] : part[2])
                               : ((o & 1) ? part[1] : part[0]);
      if (o < 4) sAct[buf][mt*16 + 4*gq + o][wave] = pv;
    }

    block_sync_lds();   // B2: partials visible; sH reads done (WAR for t+1)

    // act = sum of 4 member partials + b3
#pragma unroll
    for (int mt = 0; mt < 2; ++mt) {
      v4f pa = *(const v4f*)&sAct[buf][mt*16 + o][0];
      act[mt] = ((pa[0] + pa[1]) + (pa[2] + pa[3])) + b3v;
    }
    if (wave == 0 && gq == 0) {
#pragma unroll
      for (int mt = 0; mt < 2; ++mt)
        sOut[(mt*16 + o) * T + t] = act[mt];
    }
    buf ^= 1;
  }

  // ---- coalesced output flush ----
  block_sync_lds();
  float* obase = out + (size_t)row0 * T;
  for (int idx = tid; idx < BLK_ROWS * T; idx += NTHREADS)
    obase[idx] = sOut[idx];
}

}  // namespace

extern "C" void kernel_launch(void* const* d_in, const int* in_sizes, int n_in,
                              void* d_out, int out_size, void* d_ws, size_t ws_size,
                              hipStream_t stream) {
  const float* proj  = (const float*)d_in[0];
  const float* idm   = (const float*)d_in[1];
  const float* merg  = (const float*)d_in[2];
  const float* W1    = (const float*)d_in[3];
  const float* b1    = (const float*)d_in[4];
  const float* W2    = (const float*)d_in[5];
  const float* b2    = (const float*)d_in[6];
  const float* W3    = (const float*)d_in[7];
  const float* b3    = (const float*)d_in[8];
  const float* smean = (const float*)d_in[9];
  const float* svar  = (const float*)d_in[10];
  // d_in[11] = rollout_len (fixed 50)

  dim3 grid(NB / BLK_ROWS);   // 1024 blocks; 3 resident/CU + backfill
  dim3 block(NTHREADS);       // 256 threads = 4 waves, 32 rows
  hipLaunchKernelGGL(fwdsim11, grid, block, 0, stream,
                     proj, idm, merg, W1, b1, W2, b2, W3, b3, smean, svar,
                     (float*)d_out);
}